// Round 1
// baseline (2241.808 us; speedup 1.0000x reference)
//
#include <hip/hip_runtime.h>
#include <math.h>

// Attention_80779744903968 — fp32 pipeline, round 1 (correctness-first).
// B=32, T=512, S=1024, H=1024. All dims multiples of 128 -> no edge handling.
//
// Stage plan (all on `stream`):
//   K1: Z[B*T,H]   = Q · W_in^T                (NT)
//   K2: P[b][T,S]  = Z_b · enc_b^T             (NT, batched, ldb = B*H)
//   K3: row softmax over S with (x==0 -> -inf) quirk
//   K4: C[b][T,H]  = P_b · enc_b               (NN, batched)  [C overwrites Z]
//   K5: out        = tanh([C,Q] · W_out^T + b) (NT, K=2048 concat via Ksplit)

#define BM 128
#define BN 128
#define BKT 16

template<bool BT, bool DO_TANH, bool CAT_A>
__global__ __launch_bounds__(256)
void sgemm(const float* __restrict__ A, const float* __restrict__ A2,
           const float* __restrict__ Bmat, const float* __restrict__ bias,
           float* __restrict__ C,
           int M, int N, int K, int Ksplit,
           int lda, int ldb, int ldc,
           long sA, long sB, long sC)
{
    __shared__ float As[BKT][BM];   // transposed: As[k][m]
    __shared__ float Bs[BKT][BN];   // Bs[k][n]

    const int bz = blockIdx.z;
    const float* Ab = A + (long)bz * sA;
    const float* Bb = Bmat + (long)bz * sB;
    float* Cb = C + (long)bz * sC;

    const int tid = threadIdx.x;
    const int m0 = blockIdx.y * BM;
    const int n0 = blockIdx.x * BN;
    const int tx = tid & 15;       // 16 col-groups
    const int ty = tid >> 4;       // 16 row-groups

    float acc[8][8];
#pragma unroll
    for (int i = 0; i < 8; ++i)
#pragma unroll
        for (int j = 0; j < 8; ++j) acc[i][j] = 0.f;

    for (int kk = 0; kk < K; kk += BKT) {
        const float* Asrc = Ab;
        int acol = kk;
        if constexpr (CAT_A) {
            if (kk >= Ksplit) { Asrc = A2; acol = kk - Ksplit; }
        }
        // --- stage A tile: 128 rows x 16 k, K-contiguous source, transpose into LDS
#pragma unroll
        for (int i = 0; i < 2; ++i) {
            int f = i * 256 + tid;          // 0..511 float4 slots, fully coalesced
            int row = f >> 2;               // 0..127
            int k4 = (f & 3) << 2;          // 0,4,8,12
            float4 v = *(const float4*)(Asrc + (long)(m0 + row) * lda + acol + k4);
            As[k4 + 0][row] = v.x;
            As[k4 + 1][row] = v.y;
            As[k4 + 2][row] = v.z;
            As[k4 + 3][row] = v.w;
        }
        // --- stage B tile
        if constexpr (BT) {
            // B[n,k], K-contiguous rows
#pragma unroll
            for (int i = 0; i < 2; ++i) {
                int f = i * 256 + tid;
                int row = f >> 2;           // n 0..127
                int k4 = (f & 3) << 2;
                float4 v = *(const float4*)(Bb + (long)(n0 + row) * ldb + kk + k4);
                Bs[k4 + 0][row] = v.x;
                Bs[k4 + 1][row] = v.y;
                Bs[k4 + 2][row] = v.z;
                Bs[k4 + 3][row] = v.w;
            }
        } else {
            // B[k,n], N-contiguous rows -> direct float4 into LDS
#pragma unroll
            for (int i = 0; i < 2; ++i) {
                int f = i * 256 + tid;
                int kr = f >> 5;            // 0..15
                int n4 = (f & 31) << 2;     // 0..124
                float4 v = *(const float4*)(Bb + (long)(kk + kr) * ldb + n0 + n4);
                *(float4*)&Bs[kr][n4] = v;
            }
        }
        __syncthreads();

#pragma unroll
        for (int k = 0; k < BKT; ++k) {
            float a[8], bv[8];
            // split 64-offset micro-tile: LDS reads are broadcast / 2-way (free)
            *(float4*)&a[0]  = *(const float4*)&As[k][ty * 4];
            *(float4*)&a[4]  = *(const float4*)&As[k][ty * 4 + 64];
            *(float4*)&bv[0] = *(const float4*)&Bs[k][tx * 4];
            *(float4*)&bv[4] = *(const float4*)&Bs[k][tx * 4 + 64];
#pragma unroll
            for (int i = 0; i < 8; ++i)
#pragma unroll
                for (int j = 0; j < 8; ++j)
                    acc[i][j] = fmaf(a[i], bv[j], acc[i][j]);
        }
        __syncthreads();
    }

    // --- epilogue
#pragma unroll
    for (int i = 0; i < 8; ++i) {
        int r = m0 + ty * 4 + (i & 3) + ((i >> 2) << 6);
        float* crow = Cb + (long)r * ldc;
#pragma unroll
        for (int jj = 0; jj < 2; ++jj) {
            int c0 = n0 + tx * 4 + jj * 64;
            float4 v;
            v.x = acc[i][jj * 4 + 0];
            v.y = acc[i][jj * 4 + 1];
            v.z = acc[i][jj * 4 + 2];
            v.w = acc[i][jj * 4 + 3];
            if constexpr (DO_TANH) {
                v.x = tanhf(v.x + bias[c0 + 0]);
                v.y = tanhf(v.y + bias[c0 + 1]);
                v.z = tanhf(v.z + bias[c0 + 2]);
                v.w = tanhf(v.w + bias[c0 + 3]);
            }
            *(float4*)(crow + c0) = v;
        }
    }
}

// One wave per row of 1024; 4 rows per 256-thread block.
// Quirk: positions where the raw score is exactly 0.0 are filled with -inf.
__global__ __launch_bounds__(256)
void softmax_rows(float* __restrict__ P)
{
    const int row = blockIdx.x * 4 + (threadIdx.x >> 6);
    const int lane = threadIdx.x & 63;
    float* p = P + (long)row * 1024 + lane * 4;

    float4 v[4];
    float mx = -INFINITY;
#pragma unroll
    for (int i = 0; i < 4; ++i) {
        v[i] = *(const float4*)(p + i * 256);
        v[i].x = (v[i].x == 0.f) ? -INFINITY : v[i].x;
        v[i].y = (v[i].y == 0.f) ? -INFINITY : v[i].y;
        v[i].z = (v[i].z == 0.f) ? -INFINITY : v[i].z;
        v[i].w = (v[i].w == 0.f) ? -INFINITY : v[i].w;
        mx = fmaxf(mx, fmaxf(fmaxf(v[i].x, v[i].y), fmaxf(v[i].z, v[i].w)));
    }
#pragma unroll
    for (int o = 32; o > 0; o >>= 1) mx = fmaxf(mx, __shfl_xor(mx, o, 64));

    float sum = 0.f;
#pragma unroll
    for (int i = 0; i < 4; ++i) {
        v[i].x = __expf(v[i].x - mx);
        v[i].y = __expf(v[i].y - mx);
        v[i].z = __expf(v[i].z - mx);
        v[i].w = __expf(v[i].w - mx);
        sum += v[i].x + v[i].y + v[i].z + v[i].w;
    }
#pragma unroll
    for (int o = 32; o > 0; o >>= 1) sum += __shfl_xor(sum, o, 64);

    const float inv = 1.f / sum;
#pragma unroll
    for (int i = 0; i < 4; ++i) {
        v[i].x *= inv; v[i].y *= inv; v[i].z *= inv; v[i].w *= inv;
        *(float4*)(p + i * 256) = v[i];
    }
}

extern "C" void kernel_launch(void* const* d_in, const int* in_sizes, int n_in,
                              void* d_out, int out_size, void* d_ws, size_t ws_size,
                              hipStream_t stream)
{
    (void)in_sizes; (void)n_in; (void)out_size; (void)ws_size;
    const int Bv = 32, T = 512, S = 1024, H = 1024;

    const float* q     = (const float*)d_in[0];
    const float* enc   = (const float*)d_in[1];
    // d_in[2] src_lengths: computed-but-unused in the reference — ignored.
    const float* W_in  = (const float*)d_in[3];
    const float* W_out = (const float*)d_in[4];
    const float* b_out = (const float*)d_in[5];
    float* out = (float*)d_out;

    // Workspace: Z [B*T,H] (64 MB, later reused as context C) + P [B,T,S] (64 MB)
    float* Z = (float*)d_ws;
    float* P = Z + (size_t)Bv * T * H;

    dim3 blk(256);

    // K1: Z = Q · W_in^T     (M=16384, N=1024, K=1024)
    sgemm<true, false, false><<<dim3(H / BN, (Bv * T) / BM, 1), blk, 0, stream>>>(
        q, nullptr, W_in, nullptr, Z,
        Bv * T, H, H, 0, H, H, H, 0, 0, 0);

    // K2: P_b = Z_b · enc_b^T  (batched over b; enc[s,b,i] -> base b*H, ldb=B*H)
    sgemm<true, false, false><<<dim3(S / BN, T / BM, Bv), blk, 0, stream>>>(
        Z, nullptr, enc, nullptr, P,
        T, S, H, 0, H, Bv * H, S, (long)T * H, H, (long)T * S);

    // K3: masked softmax over S
    softmax_rows<<<(Bv * T) / 4, blk, 0, stream>>>(P);

    // K4: C_b = P_b · enc_b    (NN; C overwrites Z)
    sgemm<false, false, false><<<dim3(H / BN, T / BM, Bv), blk, 0, stream>>>(
        P, nullptr, enc, nullptr, Z,
        T, H, S, 0, S, Bv * H, H, (long)T * S, H, (long)T * H);

    // K5: out = tanh([C,Q] · W_out^T + b_out)   (K=2048, split at 1024)
    sgemm<true, true, true><<<dim3(H / BN, (Bv * T) / BM, 1), blk, 0, stream>>>(
        Z, q, W_out, b_out, out,
        Bv * T, H, 2 * H, H, H, 2 * H, H, 0, 0, 0);
}

// Round 2
// 758.338 us; speedup vs baseline: 2.9562x; 2.9562x over previous
//
#include <hip/hip_runtime.h>
#include <math.h>

// Attention_80779744903968 — round 2: bf16-MFMA pipeline with bf16x3 (hi/lo
// split) precision for the softmax-critical GEMMs.
//
//   split: q->q_hi/q_lo, W_in->hi/lo, W_out->hi, enc->e_hi/e_lo
//   K1: z  = q·W_in^T       bf16x3 (3 chunks K=1024), out: z_hi/z_lo bf16
//   K2: P  = z·enc^T        bf16x3, batched, out fp32 -> d_out (reused as scratch)
//   K3: softmax rows (==0 -> -inf quirk), out: Pb bf16
//   T : e_hi [S,B,H] -> eT [B][H][S]
//   K4: C  = Pb·enc         bf16 (1 chunk), out C_hi bf16
//   K5: out= tanh([C,q]·W_out^T + b)   bf16 (2 chunks), fp32 -> d_out
//
// Workspace 264 MiB; falls back to the verified round-1 fp32 path if ws_size
// is too small.

// ---------------------------------------------------------------- helpers
__device__ inline unsigned short f2bf(float x) {           // RNE float->bf16
    unsigned int u = __float_as_uint(x);
    u += 0x7fffu + ((u >> 16) & 1u);
    return (unsigned short)(u >> 16);
}
__device__ inline float bf2f(unsigned short h) {
    return __uint_as_float(((unsigned int)h) << 16);
}

typedef __attribute__((ext_vector_type(8))) short short8;  // 8 bf16 (4 VGPRs)
typedef __attribute__((ext_vector_type(4))) float f32x4;

__device__ inline void gld_lds16(const void* g, void* l) {
    // async global->LDS, 16B/lane; LDS dest = wave-uniform base + lane*16
    __builtin_amdgcn_global_load_lds(
        (const __attribute__((address_space(1))) unsigned int*)g,
        (__attribute__((address_space(3))) unsigned int*)l, 16, 0, 0);
}

// LDS tile layout: [row][granule] with granule g stored at g ^ (row&7)
// (16B granules). Breaks the 128B-row-stride bank collision down to 2-way.
__device__ inline short8 frag_ld(const short* Ls, int rowbase, int ks8, int lane) {
    const int r = lane & 15;
    const int q = lane >> 4;
    return *(const short8*)&Ls[(rowbase + r) * 64 + (((ks8 + q) ^ (r & 7)) << 3)];
}

// ---------------------------------------------------------------- MFMA GEMM
// C[m][n] = sum_c sum_k Ac[m][k] * Bc[n][k]   (both operands k-contiguous, NT)
// 128x128 tile, 4 waves, each wave 64x64 via 4x4 of 16x16x32 bf16 MFMA, BK=64.
// OUT_MODE: 0 = bf16(Oh), 1 = hi/lo bf16 (Oh,Ol), 2 = fp32(Of),
//           3 = fp32 tanh(acc + bias[col]) (Of)
template<int NCHUNK, int OUT_MODE>
__global__ __launch_bounds__(256, 2)
void gemm_mfma(const unsigned short* __restrict__ A0, const unsigned short* __restrict__ A1,
               const unsigned short* __restrict__ A2,
               const unsigned short* __restrict__ B0, const unsigned short* __restrict__ B1,
               const unsigned short* __restrict__ B2,
               float* __restrict__ Of, unsigned short* __restrict__ Oh,
               unsigned short* __restrict__ Ol, const float* __restrict__ bias,
               int chunkK, long lda, long ldb, long ldc, long sA, long sB, long sC)
{
    __shared__ short As[128 * 64];
    __shared__ short Bs[128 * 64];

    const int tid  = threadIdx.x;
    const int wave = tid >> 6, lane = tid & 63;
    const int wm = (wave & 1) << 6, wn = (wave >> 1) << 6;
    const long m0 = (long)blockIdx.y * 128, n0 = (long)blockIdx.x * 128;
    const int bz = blockIdx.z;

    const unsigned short* Ap[3] = {A0, A1, A2};
    const unsigned short* Bp[3] = {B0, B1, B2};

    f32x4 acc[4][4];
#pragma unroll
    for (int i = 0; i < 4; ++i)
#pragma unroll
        for (int j = 0; j < 4; ++j) acc[i][j] = (f32x4){0.f, 0.f, 0.f, 0.f};

    const int lr   = lane >> 3;            // 0..7
    const int gran = (lane & 7) ^ lr;      // swizzled granule this lane fetches
    const int rw   = wave * 32;            // this wave's row chunk

#pragma unroll
    for (int c = 0; c < NCHUNK; ++c) {
        const unsigned short* Ac = Ap[c] + (long)bz * sA + m0 * lda;
        const unsigned short* Bc = Bp[c] + (long)bz * sB + n0 * ldb;
        for (int k0 = 0; k0 < chunkK; k0 += 64) {
            __syncthreads();
#pragma unroll
            for (int seg = 0; seg < 4; ++seg) {
                const int row = rw + seg * 8 + lr;
                gld_lds16(Ac + (long)row * lda + k0 + (gran << 3),
                          As + (rw + seg * 8) * 64);
            }
#pragma unroll
            for (int seg = 0; seg < 4; ++seg) {
                const int row = rw + seg * 8 + lr;
                gld_lds16(Bc + (long)row * ldb + k0 + (gran << 3),
                          Bs + (rw + seg * 8) * 64);
            }
            __syncthreads();
#pragma unroll
            for (int ks = 0; ks < 2; ++ks) {
                short8 af[4], bfv[4];
#pragma unroll
                for (int i = 0; i < 4; ++i) af[i]  = frag_ld(As, wm + i * 16, ks * 4, lane);
#pragma unroll
                for (int j = 0; j < 4; ++j) bfv[j] = frag_ld(Bs, wn + j * 16, ks * 4, lane);
#pragma unroll
                for (int i = 0; i < 4; ++i)
#pragma unroll
                    for (int j = 0; j < 4; ++j)
                        acc[i][j] = __builtin_amdgcn_mfma_f32_16x16x32_bf16(
                            af[i], bfv[j], acc[i][j], 0, 0, 0);
            }
        }
    }

    // epilogue — C/D layout: col = lane&15, row = (lane>>4)*4 + reg (m89-verified)
    const int q = lane >> 4, r = lane & 15;
#pragma unroll
    for (int i = 0; i < 4; ++i) {
#pragma unroll
        for (int rr = 0; rr < 4; ++rr) {
            const long grow = m0 + wm + i * 16 + q * 4 + rr;
#pragma unroll
            for (int j = 0; j < 4; ++j) {
                const long gcol = n0 + wn + j * 16 + r;
                const float v = acc[i][j][rr];
                const long off = (long)bz * sC + grow * ldc + gcol;
                if constexpr (OUT_MODE == 0) {
                    Oh[off] = f2bf(v);
                } else if constexpr (OUT_MODE == 1) {
                    unsigned short h = f2bf(v);
                    Oh[off] = h;
                    Ol[off] = f2bf(v - bf2f(h));
                } else if constexpr (OUT_MODE == 2) {
                    Of[off] = v;
                } else {
                    Of[off] = tanhf(v + bias[gcol]);
                }
            }
        }
    }
}

// ---------------------------------------------------------------- casts
template<bool HAS_LO>
__global__ __launch_bounds__(256)
void split_f32_bf16(const float* __restrict__ x, unsigned short* __restrict__ hi,
                    unsigned short* __restrict__ lo, int n4)
{
    const int i = blockIdx.x * 256 + threadIdx.x;
    if (i >= n4) return;
    const float4 v = ((const float4*)x)[i];
    ushort4 h;
    h.x = f2bf(v.x); h.y = f2bf(v.y); h.z = f2bf(v.z); h.w = f2bf(v.w);
    ((ushort4*)hi)[i] = h;
    if constexpr (HAS_LO) {
        ushort4 l;
        l.x = f2bf(v.x - bf2f(h.x)); l.y = f2bf(v.y - bf2f(h.y));
        l.z = f2bf(v.z - bf2f(h.z)); l.w = f2bf(v.w - bf2f(h.w));
        ((ushort4*)lo)[i] = l;
    }
}

// e_hi [S,B,H] -> eT [B][H][S]; 64x64 tiles, B=32,H=1024,S=1024 fixed
__global__ __launch_bounds__(256)
void transpose_enc(const unsigned short* __restrict__ E, unsigned short* __restrict__ ET)
{
    __shared__ unsigned short L[64][72];
    const int s0 = blockIdx.x * 64, h0 = blockIdx.y * 64, b = blockIdx.z;
    const int tid = threadIdx.x;
#pragma unroll
    for (int io = 0; io < 2; ++io) {
        const int g = io * 256 + tid;
        const int rs = g >> 3, c8 = (g & 7) * 8;
        const unsigned short* src = E + ((long)(s0 + rs) * 32 + b) * 1024 + h0 + c8;
        *(ushort4*)&L[rs][c8]     = *(const ushort4*)(src);
        *(ushort4*)&L[rs][c8 + 4] = *(const ushort4*)(src + 4);
    }
    __syncthreads();
#pragma unroll
    for (int io = 0; io < 2; ++io) {
        const int g = io * 256 + tid;
        const int rh = g >> 3, c8 = (g & 7) * 8;
        unsigned short t[8];
#pragma unroll
        for (int j = 0; j < 8; ++j) t[j] = L[c8 + j][rh];
        unsigned short* dst = ET + ((long)b * 1024 + h0 + rh) * 1024 + s0 + c8;
        *(ushort4*)(dst)     = *(const ushort4*)&t[0];
        *(ushort4*)(dst + 4) = *(const ushort4*)&t[4];
    }
}

// ------------------------------------------------------------ softmax (bf16 out)
__global__ __launch_bounds__(256)
void softmax_p_bf16(const float* __restrict__ P, unsigned short* __restrict__ Pb)
{
    const int row  = blockIdx.x * 4 + (threadIdx.x >> 6);
    const int lane = threadIdx.x & 63;
    const float* p = P + (long)row * 1024 + lane * 4;
    unsigned short* pb = Pb + (long)row * 1024 + lane * 4;

    float4 v[4];
    float mx = -INFINITY;
#pragma unroll
    for (int i = 0; i < 4; ++i) {
        v[i] = *(const float4*)(p + i * 256);
        v[i].x = (v[i].x == 0.f) ? -INFINITY : v[i].x;
        v[i].y = (v[i].y == 0.f) ? -INFINITY : v[i].y;
        v[i].z = (v[i].z == 0.f) ? -INFINITY : v[i].z;
        v[i].w = (v[i].w == 0.f) ? -INFINITY : v[i].w;
        mx = fmaxf(mx, fmaxf(fmaxf(v[i].x, v[i].y), fmaxf(v[i].z, v[i].w)));
    }
#pragma unroll
    for (int o = 32; o > 0; o >>= 1) mx = fmaxf(mx, __shfl_xor(mx, o, 64));

    float sum = 0.f;
#pragma unroll
    for (int i = 0; i < 4; ++i) {
        v[i].x = __expf(v[i].x - mx);
        v[i].y = __expf(v[i].y - mx);
        v[i].z = __expf(v[i].z - mx);
        v[i].w = __expf(v[i].w - mx);
        sum += v[i].x + v[i].y + v[i].z + v[i].w;
    }
#pragma unroll
    for (int o = 32; o > 0; o >>= 1) sum += __shfl_xor(sum, o, 64);

    const float inv = 1.f / sum;
#pragma unroll
    for (int i = 0; i < 4; ++i) {
        ushort4 u;
        u.x = f2bf(v[i].x * inv); u.y = f2bf(v[i].y * inv);
        u.z = f2bf(v[i].z * inv); u.w = f2bf(v[i].w * inv);
        *(ushort4*)(pb + i * 256) = u;
    }
}

// ================================================================ fallback
// (verified round-1 fp32 path, used only if ws_size < 264 MiB)
#define BM 128
#define BN 128
#define BKT 16

template<bool BT, bool DO_TANH, bool CAT_A>
__global__ __launch_bounds__(256)
void sgemm(const float* __restrict__ A, const float* __restrict__ A2,
           const float* __restrict__ Bmat, const float* __restrict__ bias,
           float* __restrict__ C,
           int M, int N, int K, int Ksplit,
           int lda, int ldb, int ldc,
           long sA, long sB, long sC)
{
    __shared__ float Asb[BKT][BM];
    __shared__ float Bsb[BKT][BN];

    const int bz = blockIdx.z;
    const float* Ab = A + (long)bz * sA;
    const float* Bb = Bmat + (long)bz * sB;
    float* Cb = C + (long)bz * sC;

    const int tid = threadIdx.x;
    const int m0 = blockIdx.y * BM;
    const int n0 = blockIdx.x * BN;
    const int tx = tid & 15;
    const int ty = tid >> 4;

    float acc[8][8];
#pragma unroll
    for (int i = 0; i < 8; ++i)
#pragma unroll
        for (int j = 0; j < 8; ++j) acc[i][j] = 0.f;

    for (int kk = 0; kk < K; kk += BKT) {
        const float* Asrc = Ab;
        int acol = kk;
        if constexpr (CAT_A) {
            if (kk >= Ksplit) { Asrc = A2; acol = kk - Ksplit; }
        }
#pragma unroll
        for (int i = 0; i < 2; ++i) {
            int f = i * 256 + tid;
            int row = f >> 2;
            int k4 = (f & 3) << 2;
            float4 v = *(const float4*)(Asrc + (long)(m0 + row) * lda + acol + k4);
            Asb[k4 + 0][row] = v.x; Asb[k4 + 1][row] = v.y;
            Asb[k4 + 2][row] = v.z; Asb[k4 + 3][row] = v.w;
        }
        if constexpr (BT) {
#pragma unroll
            for (int i = 0; i < 2; ++i) {
                int f = i * 256 + tid;
                int row = f >> 2;
                int k4 = (f & 3) << 2;
                float4 v = *(const float4*)(Bb + (long)(n0 + row) * ldb + kk + k4);
                Bsb[k4 + 0][row] = v.x; Bsb[k4 + 1][row] = v.y;
                Bsb[k4 + 2][row] = v.z; Bsb[k4 + 3][row] = v.w;
            }
        } else {
#pragma unroll
            for (int i = 0; i < 2; ++i) {
                int f = i * 256 + tid;
                int kr = f >> 5;
                int n4 = (f & 31) << 2;
                float4 v = *(const float4*)(Bb + (long)(kk + kr) * ldb + n0 + n4);
                *(float4*)&Bsb[kr][n4] = v;
            }
        }
        __syncthreads();
#pragma unroll
        for (int k = 0; k < BKT; ++k) {
            float a[8], bv[8];
            *(float4*)&a[0]  = *(const float4*)&Asb[k][ty * 4];
            *(float4*)&a[4]  = *(const float4*)&Asb[k][ty * 4 + 64];
            *(float4*)&bv[0] = *(const float4*)&Bsb[k][tx * 4];
            *(float4*)&bv[4] = *(const float4*)&Bsb[k][tx * 4 + 64];
#pragma unroll
            for (int i = 0; i < 8; ++i)
#pragma unroll
                for (int j = 0; j < 8; ++j)
                    acc[i][j] = fmaf(a[i], bv[j], acc[i][j]);
        }
        __syncthreads();
    }
#pragma unroll
    for (int i = 0; i < 8; ++i) {
        int rrow = m0 + ty * 4 + (i & 3) + ((i >> 2) << 6);
        float* crow = Cb + (long)rrow * ldc;
#pragma unroll
        for (int jj = 0; jj < 2; ++jj) {
            int c0 = n0 + tx * 4 + jj * 64;
            float4 v;
            v.x = acc[i][jj * 4 + 0]; v.y = acc[i][jj * 4 + 1];
            v.z = acc[i][jj * 4 + 2]; v.w = acc[i][jj * 4 + 3];
            if constexpr (DO_TANH) {
                v.x = tanhf(v.x + bias[c0 + 0]); v.y = tanhf(v.y + bias[c0 + 1]);
                v.z = tanhf(v.z + bias[c0 + 2]); v.w = tanhf(v.w + bias[c0 + 3]);
            }
            *(float4*)(crow + c0) = v;
        }
    }
}

__global__ __launch_bounds__(256)
void softmax_rows(float* __restrict__ P)
{
    const int row = blockIdx.x * 4 + (threadIdx.x >> 6);
    const int lane = threadIdx.x & 63;
    float* p = P + (long)row * 1024 + lane * 4;
    float4 v[4];
    float mx = -INFINITY;
#pragma unroll
    for (int i = 0; i < 4; ++i) {
        v[i] = *(const float4*)(p + i * 256);
        v[i].x = (v[i].x == 0.f) ? -INFINITY : v[i].x;
        v[i].y = (v[i].y == 0.f) ? -INFINITY : v[i].y;
        v[i].z = (v[i].z == 0.f) ? -INFINITY : v[i].z;
        v[i].w = (v[i].w == 0.f) ? -INFINITY : v[i].w;
        mx = fmaxf(mx, fmaxf(fmaxf(v[i].x, v[i].y), fmaxf(v[i].z, v[i].w)));
    }
#pragma unroll
    for (int o = 32; o > 0; o >>= 1) mx = fmaxf(mx, __shfl_xor(mx, o, 64));
    float sum = 0.f;
#pragma unroll
    for (int i = 0; i < 4; ++i) {
        v[i].x = __expf(v[i].x - mx); v[i].y = __expf(v[i].y - mx);
        v[i].z = __expf(v[i].z - mx); v[i].w = __expf(v[i].w - mx);
        sum += v[i].x + v[i].y + v[i].z + v[i].w;
    }
#pragma unroll
    for (int o = 32; o > 0; o >>= 1) sum += __shfl_xor(sum, o, 64);
    const float inv = 1.f / sum;
#pragma unroll
    for (int i = 0; i < 4; ++i) {
        v[i].x *= inv; v[i].y *= inv; v[i].z *= inv; v[i].w *= inv;
        *(float4*)(p + i * 256) = v[i];
    }
}

// ================================================================ launch
extern "C" void kernel_launch(void* const* d_in, const int* in_sizes, int n_in,
                              void* d_out, int out_size, void* d_ws, size_t ws_size,
                              hipStream_t stream)
{
    (void)in_sizes; (void)n_in; (void)out_size;
    const int Bv = 32, T = 512, S = 1024, H = 1024;

    const float* q     = (const float*)d_in[0];
    const float* enc   = (const float*)d_in[1];
    const float* W_in  = (const float*)d_in[3];
    const float* W_out = (const float*)d_in[4];
    const float* b_out = (const float*)d_in[5];
    float* out = (float*)d_out;

    const size_t need = 264ull << 20;   // 276,824,064 B
    if (ws_size >= need) {
        char* w = (char*)d_ws;
        unsigned short* q_hi  = (unsigned short*)(w);                  // 32Mi, ->K1,K5
        unsigned short* q_lo  = (unsigned short*)(w + (32ull << 20));  // 32Mi, ->K1; then Pb
        unsigned short* z_hi  = (unsigned short*)(w + (64ull << 20));  // 32Mi, ->K2; then C_hi
        unsigned short* z_lo  = (unsigned short*)(w + (96ull << 20));  // 32Mi, ->K2
        unsigned short* e_hi  = (unsigned short*)(w + (128ull << 20)); // 64Mi, ->K2,transpose
        unsigned short* e_lo  = (unsigned short*)(w + (192ull << 20)); // 64Mi, ->K2; then eT
        unsigned short* Wi_hi = (unsigned short*)(w + (256ull << 20)); // 2Mi
        unsigned short* Wi_lo = (unsigned short*)(w + (258ull << 20)); // 2Mi
        unsigned short* Wo_hi = (unsigned short*)(w + (260ull << 20)); // 4Mi

        split_f32_bf16<true ><<<16384, 256, 0, stream>>>(q, q_hi, q_lo, 4194304);
        split_f32_bf16<true ><<<1024,  256, 0, stream>>>(W_in, Wi_hi, Wi_lo, 262144);
        split_f32_bf16<false><<<2048,  256, 0, stream>>>(W_out, Wo_hi, nullptr, 524288);
        split_f32_bf16<true ><<<32768, 256, 0, stream>>>(enc, e_hi, e_lo, 8388608);

        // K1: z = q·W_in^T  (bf16x3): hi·hi + hi·lo + lo·hi
        gemm_mfma<3, 1><<<dim3(8, 128, 1), 256, 0, stream>>>(
            q_hi, q_hi, q_lo, Wi_hi, Wi_lo, Wi_hi,
            nullptr, z_hi, z_lo, nullptr,
            1024, 1024, 1024, 1024, 0, 0, 0);

        // K2: P_b = z_b·enc_b^T (bf16x3); enc read in-place [S,B,H]: ldb=B*H, sB=H
        gemm_mfma<3, 2><<<dim3(8, 4, 32), 256, 0, stream>>>(
            z_hi, z_hi, z_lo, e_hi, e_lo, e_hi,
            (float*)d_out, nullptr, nullptr, nullptr,
            1024, 1024, (long)Bv * H, 1024,
            (long)T * H, (long)H, (long)T * S);

        // K3: masked softmax, fp32 -> bf16 (Pb overlays q_lo)
        softmax_p_bf16<<<(Bv * T) / 4, 256, 0, stream>>>((const float*)d_out, q_lo);

        // T: e_hi [S,B,H] -> eT [B][H][S] (overlays e_lo)
        transpose_enc<<<dim3(16, 16, 32), 256, 0, stream>>>(e_hi, e_lo);

        // K4: C_b = Pb_b · enc_b  (NT vs eT); C_hi overlays z_hi
        gemm_mfma<1, 0><<<dim3(8, 4, 32), 256, 0, stream>>>(
            q_lo, nullptr, nullptr, e_lo, nullptr, nullptr,
            nullptr, z_hi, nullptr, nullptr,
            1024, 1024, 1024, 1024,
            (long)T * S, (long)H * S, (long)T * H);

        // K5: out = tanh([C,q]·W_out^T + b)  (2 chunks of K=1024)
        gemm_mfma<2, 3><<<dim3(8, 128, 1), 256, 0, stream>>>(
            z_hi, q_hi, nullptr, Wo_hi, Wo_hi + 1024, nullptr,
            (float*)d_out, nullptr, nullptr, b_out,
            1024, 1024, 2048, 1024, 0, 0, 0);
    } else {
        // -------- fallback: round-1 fp32 path (needs 128 MiB) --------
        float* Z = (float*)d_ws;
        float* P = Z + (size_t)Bv * T * H;
        dim3 blk(256);
        sgemm<true, false, false><<<dim3(H / BN, (Bv * T) / BM, 1), blk, 0, stream>>>(
            q, nullptr, W_in, nullptr, Z,
            Bv * T, H, H, 0, H, H, H, 0, 0, 0);
        sgemm<true, false, false><<<dim3(S / BN, T / BM, Bv), blk, 0, stream>>>(
            Z, nullptr, enc, nullptr, P,
            T, S, H, 0, H, Bv * H, S, (long)T * H, H, (long)T * S);
        softmax_rows<<<(Bv * T) / 4, blk, 0, stream>>>(P);
        sgemm<false, false, false><<<dim3(H / BN, T / BM, Bv), blk, 0, stream>>>(
            P, nullptr, enc, nullptr, Z,
            T, H, S, 0, S, Bv * H, H, (long)T * S, H, (long)T * H);
        sgemm<true, true, true><<<dim3(H / BN, (Bv * T) / BM, 1), blk, 0, stream>>>(
            Z, q, W_out, b_out, out,
            Bv * T, H, 2 * H, H, H, 2 * H, H, 0, 0, 0);
    }
}

// Round 3
// 725.053 us; speedup vs baseline: 3.0919x; 1.0459x over previous
//
#include <hip/hip_runtime.h>
#include <math.h>

// Attention_80779744903968 — round 3:
//   * chunk-fused bf16x3 GEMM (stage hi+lo tiles once, 3 MFMA products per
//     staging, 96 MFMA per barrier pair) for K1/K2
//   * fp16 operands for K4/K5 (8x less rounding noise than bf16, same rate)
//
//   splits: q->q_hi/q_lo (bf16), W_in->hi/lo (bf16), W_out->fp16, enc->hi/lo
//   K1: z  = q·W_in^T        bf16x3 fused, out z_hi/z_lo bf16
//   K2: P  = z·enc^T         bf16x3 fused, batched, fp32 -> d_out
//   K3: softmax (==0 -> -inf quirk), fp32 -> Pb fp16
//   Q : q fp32 -> q_f16                      (into z_lo slot)
//   T : enc fp32 [S,B,H] -> eT fp16 [B][H][S] (into e_lo slot)
//   K4: C  = Pb·eT^T         fp16, out C_f16  (into z_hi slot)
//   K5: out= tanh([C,q]·W_out^T + b)  fp16 2-chunk, fp32 -> d_out

// ---------------------------------------------------------------- helpers
__device__ inline unsigned short f2bf(float x) {           // RNE float->bf16
    unsigned int u = __float_as_uint(x);
    u += 0x7fffu + ((u >> 16) & 1u);
    return (unsigned short)(u >> 16);
}
__device__ inline float bf2f(unsigned short h) {
    return __uint_as_float(((unsigned int)h) << 16);
}
__device__ inline unsigned short f2h(float x) {            // RNE float->fp16
    _Float16 h = (_Float16)x;
    return *(unsigned short*)&h;
}

typedef __attribute__((ext_vector_type(8))) short    short8; // 8 bf16
typedef __attribute__((ext_vector_type(8))) _Float16 half8;  // 8 fp16
typedef __attribute__((ext_vector_type(4))) float    f32x4;

__device__ inline void gld_lds16(const void* g, void* l) {
    __builtin_amdgcn_global_load_lds(
        (const __attribute__((address_space(1))) unsigned int*)g,
        (__attribute__((address_space(3))) unsigned int*)l, 16, 0, 0);
}

// LDS tile layout: [row][granule], granule g of row r stored at slot g^(r&7)
// (16B granules) -> frag reads are <=2-way conflicts (free, m136).
__device__ inline short8 frag_ld(const short* Ls, int rowbase, int ks8, int lane) {
    const int r = lane & 15, q = lane >> 4;
    return *(const short8*)&Ls[(rowbase + r) * 64 + (((ks8 + q) ^ (r & 7)) << 3)];
}
__device__ inline half8 frag_ld_h(const short* Ls, int rowbase, int ks8, int lane) {
    const int r = lane & 15, q = lane >> 4;
    return *(const half8*)&Ls[(rowbase + r) * 64 + (((ks8 + q) ^ (r & 7)) << 3)];
}

// stage one 128x64-short tile; each wave covers rows rw..rw+31
__device__ inline void stage_tile(const unsigned short* g, long ld, short* lds,
                                  int rw, int lr, int gran) {
#pragma unroll
    for (int seg = 0; seg < 4; ++seg) {
        const int row = rw + seg * 8 + lr;
        gld_lds16(g + (long)row * ld + (gran << 3), lds + (rw + seg * 8) * 64);
    }
}

// ------------------------------------------------- chunk-fused bf16x3 GEMM
// C = Ah·Bh^T + Ah·Bl^T + Al·Bh^T  (all K-contiguous rows, NT)
// 128x128 tile, 4 waves x (4x4 of 16x16x32 bf16), BK=64, 64 KB LDS.
// OUT_MODE: 1 = hi/lo bf16 split out, 2 = fp32 out
template<int OUT_MODE>
__global__ __launch_bounds__(256, 2)
void gemm_x3(const unsigned short* __restrict__ Ahg, const unsigned short* __restrict__ Alg,
             const unsigned short* __restrict__ Bhg, const unsigned short* __restrict__ Blg,
             float* __restrict__ Of, unsigned short* __restrict__ Oh,
             unsigned short* __restrict__ Ol,
             int K, long lda, long ldb, long ldc, long sA, long sB, long sC)
{
    __shared__ short Ah[128 * 64], Al[128 * 64], Bh[128 * 64], Bl[128 * 64];

    const int tid  = threadIdx.x;
    const int wave = tid >> 6, lane = tid & 63;
    const int wm = (wave & 1) << 6, wn = (wave >> 1) << 6;
    const long m0 = (long)blockIdx.y * 128, n0 = (long)blockIdx.x * 128;
    const int bz = blockIdx.z;

    const unsigned short* Ah0 = Ahg + (long)bz * sA + m0 * lda;
    const unsigned short* Al0 = Alg + (long)bz * sA + m0 * lda;
    const unsigned short* Bh0 = Bhg + (long)bz * sB + n0 * ldb;
    const unsigned short* Bl0 = Blg + (long)bz * sB + n0 * ldb;

    f32x4 acc[4][4];
#pragma unroll
    for (int i = 0; i < 4; ++i)
#pragma unroll
        for (int j = 0; j < 4; ++j) acc[i][j] = (f32x4){0.f, 0.f, 0.f, 0.f};

    const int lr   = lane >> 3;
    const int gran = (lane & 7) ^ lr;
    const int rw   = wave * 32;

    for (int k0 = 0; k0 < K; k0 += 64) {
        __syncthreads();
        stage_tile(Ah0 + k0, lda, Ah, rw, lr, gran);
        stage_tile(Al0 + k0, lda, Al, rw, lr, gran);
        stage_tile(Bh0 + k0, ldb, Bh, rw, lr, gran);
        stage_tile(Bl0 + k0, ldb, Bl, rw, lr, gran);
        __syncthreads();
#pragma unroll
        for (int ks = 0; ks < 2; ++ks) {
            short8 ah[4], al[4], bh[4], bl[4];
#pragma unroll
            for (int i = 0; i < 4; ++i) ah[i] = frag_ld(Ah, wm + i * 16, ks * 4, lane);
#pragma unroll
            for (int j = 0; j < 4; ++j) bh[j] = frag_ld(Bh, wn + j * 16, ks * 4, lane);
#pragma unroll
            for (int i = 0; i < 4; ++i)
#pragma unroll
                for (int j = 0; j < 4; ++j)
                    acc[i][j] = __builtin_amdgcn_mfma_f32_16x16x32_bf16(ah[i], bh[j], acc[i][j], 0, 0, 0);
#pragma unroll
            for (int j = 0; j < 4; ++j) bl[j] = frag_ld(Bl, wn + j * 16, ks * 4, lane);
#pragma unroll
            for (int i = 0; i < 4; ++i)
#pragma unroll
                for (int j = 0; j < 4; ++j)
                    acc[i][j] = __builtin_amdgcn_mfma_f32_16x16x32_bf16(ah[i], bl[j], acc[i][j], 0, 0, 0);
#pragma unroll
            for (int i = 0; i < 4; ++i) al[i] = frag_ld(Al, wm + i * 16, ks * 4, lane);
#pragma unroll
            for (int i = 0; i < 4; ++i)
#pragma unroll
                for (int j = 0; j < 4; ++j)
                    acc[i][j] = __builtin_amdgcn_mfma_f32_16x16x32_bf16(al[i], bh[j], acc[i][j], 0, 0, 0);
        }
    }

    // epilogue — C/D map: col = lane&15, row = (lane>>4)*4 + reg (m89)
    const int q = lane >> 4, r = lane & 15;
#pragma unroll
    for (int i = 0; i < 4; ++i)
#pragma unroll
        for (int rr = 0; rr < 4; ++rr) {
            const long grow = m0 + wm + i * 16 + q * 4 + rr;
#pragma unroll
            for (int j = 0; j < 4; ++j) {
                const long gcol = n0 + wn + j * 16 + r;
                const float v = acc[i][j][rr];
                const long off = (long)bz * sC + grow * ldc + gcol;
                if constexpr (OUT_MODE == 1) {
                    unsigned short h = f2bf(v);
                    Oh[off] = h;
                    Ol[off] = f2bf(v - bf2f(h));
                } else {
                    Of[off] = v;
                }
            }
        }
}

// ------------------------------------------------- fp16 GEMM (K4 / K5)
// C = sum_c Ac·Bc^T ; OUT_MODE: 0 = fp16 out, 3 = tanh(acc+bias) fp32 out
template<int NCHUNK, int OUT_MODE>
__global__ __launch_bounds__(256, 2)
void gemm_f16(const unsigned short* __restrict__ A0, const unsigned short* __restrict__ A1,
              const unsigned short* __restrict__ B0, const unsigned short* __restrict__ B1,
              float* __restrict__ Of, unsigned short* __restrict__ Oh,
              const float* __restrict__ bias,
              int chunkK, long lda, long ldb, long ldc, long sA, long sB, long sC)
{
    __shared__ short As[128 * 64];
    __shared__ short Bs[128 * 64];

    const int tid  = threadIdx.x;
    const int wave = tid >> 6, lane = tid & 63;
    const int wm = (wave & 1) << 6, wn = (wave >> 1) << 6;
    const long m0 = (long)blockIdx.y * 128, n0 = (long)blockIdx.x * 128;
    const int bz = blockIdx.z;

    const unsigned short* Ap[2] = {A0, A1};
    const unsigned short* Bp[2] = {B0, B1};

    f32x4 acc[4][4];
#pragma unroll
    for (int i = 0; i < 4; ++i)
#pragma unroll
        for (int j = 0; j < 4; ++j) acc[i][j] = (f32x4){0.f, 0.f, 0.f, 0.f};

    const int lr   = lane >> 3;
    const int gran = (lane & 7) ^ lr;
    const int rw   = wave * 32;

#pragma unroll
    for (int c = 0; c < NCHUNK; ++c) {
        const unsigned short* Ac = Ap[c] + (long)bz * sA + m0 * lda;
        const unsigned short* Bc = Bp[c] + (long)bz * sB + n0 * ldb;
        for (int k0 = 0; k0 < chunkK; k0 += 64) {
            __syncthreads();
            stage_tile(Ac + k0, lda, As, rw, lr, gran);
            stage_tile(Bc + k0, ldb, Bs, rw, lr, gran);
            __syncthreads();
#pragma unroll
            for (int ks = 0; ks < 2; ++ks) {
                half8 af[4], bfv[4];
#pragma unroll
                for (int i = 0; i < 4; ++i) af[i]  = frag_ld_h(As, wm + i * 16, ks * 4, lane);
#pragma unroll
                for (int j = 0; j < 4; ++j) bfv[j] = frag_ld_h(Bs, wn + j * 16, ks * 4, lane);
#pragma unroll
                for (int i = 0; i < 4; ++i)
#pragma unroll
                    for (int j = 0; j < 4; ++j)
                        acc[i][j] = __builtin_amdgcn_mfma_f32_16x16x32_f16(af[i], bfv[j], acc[i][j], 0, 0, 0);
            }
        }
    }

    const int q = lane >> 4, r = lane & 15;
#pragma unroll
    for (int i = 0; i < 4; ++i)
#pragma unroll
        for (int rr = 0; rr < 4; ++rr) {
            const long grow = m0 + wm + i * 16 + q * 4 + rr;
#pragma unroll
            for (int j = 0; j < 4; ++j) {
                const long gcol = n0 + wn + j * 16 + r;
                const float v = acc[i][j][rr];
                const long off = (long)bz * sC + grow * ldc + gcol;
                if constexpr (OUT_MODE == 0) {
                    Oh[off] = f2h(v);
                } else {
                    Of[off] = tanhf(v + bias[gcol]);
                }
            }
        }
}

// ---------------------------------------------------------------- casts
template<bool HAS_LO>
__global__ __launch_bounds__(256)
void split_f32_bf16(const float* __restrict__ x, unsigned short* __restrict__ hi,
                    unsigned short* __restrict__ lo, int n4)
{
    const int i = blockIdx.x * 256 + threadIdx.x;
    if (i >= n4) return;
    const float4 v = ((const float4*)x)[i];
    ushort4 h;
    h.x = f2bf(v.x); h.y = f2bf(v.y); h.z = f2bf(v.z); h.w = f2bf(v.w);
    ((ushort4*)hi)[i] = h;
    if constexpr (HAS_LO) {
        ushort4 l;
        l.x = f2bf(v.x - bf2f(h.x)); l.y = f2bf(v.y - bf2f(h.y));
        l.z = f2bf(v.z - bf2f(h.z)); l.w = f2bf(v.w - bf2f(h.w));
        ((ushort4*)lo)[i] = l;
    }
}

__global__ __launch_bounds__(256)
void conv_f32_f16(const float* __restrict__ x, unsigned short* __restrict__ o, int n4)
{
    const int i = blockIdx.x * 256 + threadIdx.x;
    if (i >= n4) return;
    const float4 v = ((const float4*)x)[i];
    ushort4 h;
    h.x = f2h(v.x); h.y = f2h(v.y); h.z = f2h(v.z); h.w = f2h(v.w);
    ((ushort4*)o)[i] = h;
}

// enc fp32 [S,B,H] -> eT fp16 [B][H][S]; 64x64 tiles
__global__ __launch_bounds__(256)
void transpose_enc_f16(const float* __restrict__ E, unsigned short* __restrict__ ET)
{
    __shared__ unsigned short L[64][72];
    const int s0 = blockIdx.x * 64, h0 = blockIdx.y * 64, b = blockIdx.z;
    const int tid = threadIdx.x;
#pragma unroll
    for (int io = 0; io < 2; ++io) {
        const int g = io * 256 + tid;
        const int rs = g >> 3, c8 = (g & 7) * 8;
        const float* src = E + ((long)(s0 + rs) * 32 + b) * 1024 + h0 + c8;
        const float4 v0 = *(const float4*)(src);
        const float4 v1 = *(const float4*)(src + 4);
        L[rs][c8 + 0] = f2h(v0.x); L[rs][c8 + 1] = f2h(v0.y);
        L[rs][c8 + 2] = f2h(v0.z); L[rs][c8 + 3] = f2h(v0.w);
        L[rs][c8 + 4] = f2h(v1.x); L[rs][c8 + 5] = f2h(v1.y);
        L[rs][c8 + 6] = f2h(v1.z); L[rs][c8 + 7] = f2h(v1.w);
    }
    __syncthreads();
#pragma unroll
    for (int io = 0; io < 2; ++io) {
        const int g = io * 256 + tid;
        const int rh = g >> 3, c8 = (g & 7) * 8;
        unsigned short t[8];
#pragma unroll
        for (int j = 0; j < 8; ++j) t[j] = L[c8 + j][rh];
        unsigned short* dst = ET + ((long)b * 1024 + h0 + rh) * 1024 + s0 + c8;
        *(ushort4*)(dst)     = *(const ushort4*)&t[0];
        *(ushort4*)(dst + 4) = *(const ushort4*)&t[4];
    }
}

// -------------------------------------------------- softmax (fp16 out)
__global__ __launch_bounds__(256)
void softmax_p_f16(const float* __restrict__ P, unsigned short* __restrict__ Pb)
{
    const int row  = blockIdx.x * 4 + (threadIdx.x >> 6);
    const int lane = threadIdx.x & 63;
    const float* p = P + (long)row * 1024 + lane * 4;
    unsigned short* pb = Pb + (long)row * 1024 + lane * 4;

    float4 v[4];
    float mx = -INFINITY;
#pragma unroll
    for (int i = 0; i < 4; ++i) {
        v[i] = *(const float4*)(p + i * 256);
        v[i].x = (v[i].x == 0.f) ? -INFINITY : v[i].x;
        v[i].y = (v[i].y == 0.f) ? -INFINITY : v[i].y;
        v[i].z = (v[i].z == 0.f) ? -INFINITY : v[i].z;
        v[i].w = (v[i].w == 0.f) ? -INFINITY : v[i].w;
        mx = fmaxf(mx, fmaxf(fmaxf(v[i].x, v[i].y), fmaxf(v[i].z, v[i].w)));
    }
#pragma unroll
    for (int o = 32; o > 0; o >>= 1) mx = fmaxf(mx, __shfl_xor(mx, o, 64));

    float sum = 0.f;
#pragma unroll
    for (int i = 0; i < 4; ++i) {
        v[i].x = __expf(v[i].x - mx); v[i].y = __expf(v[i].y - mx);
        v[i].z = __expf(v[i].z - mx); v[i].w = __expf(v[i].w - mx);
        sum += v[i].x + v[i].y + v[i].z + v[i].w;
    }
#pragma unroll
    for (int o = 32; o > 0; o >>= 1) sum += __shfl_xor(sum, o, 64);

    const float inv = 1.f / sum;
#pragma unroll
    for (int i = 0; i < 4; ++i) {
        ushort4 u;
        u.x = f2h(v[i].x * inv); u.y = f2h(v[i].y * inv);
        u.z = f2h(v[i].z * inv); u.w = f2h(v[i].w * inv);
        *(ushort4*)(pb + i * 256) = u;
    }
}

// ================================================================ fallback
// (verified round-1 fp32 path, used only if ws_size < 264 MiB)
#define BM 128
#define BN 128
#define BKT 16

template<bool BT, bool DO_TANH, bool CAT_A>
__global__ __launch_bounds__(256)
void sgemm(const float* __restrict__ A, const float* __restrict__ A2,
           const float* __restrict__ Bmat, const float* __restrict__ bias,
           float* __restrict__ C,
           int M, int N, int K, int Ksplit,
           int lda, int ldb, int ldc,
           long sA, long sB, long sC)
{
    __shared__ float Asb[BKT][BM];
    __shared__ float Bsb[BKT][BN];

    const int bz = blockIdx.z;
    const float* Ab = A + (long)bz * sA;
    const float* Bb = Bmat + (long)bz * sB;
    float* Cb = C + (long)bz * sC;

    const int tid = threadIdx.x;
    const int m0 = blockIdx.y * BM;
    const int n0 = blockIdx.x * BN;
    const int tx = tid & 15;
    const int ty = tid >> 4;

    float acc[8][8];
#pragma unroll
    for (int i = 0; i < 8; ++i)
#pragma unroll
        for (int j = 0; j < 8; ++j) acc[i][j] = 0.f;

    for (int kk = 0; kk < K; kk += BKT) {
        const float* Asrc = Ab;
        int acol = kk;
        if constexpr (CAT_A) {
            if (kk >= Ksplit) { Asrc = A2; acol = kk - Ksplit; }
        }
#pragma unroll
        for (int i = 0; i < 2; ++i) {
            int f = i * 256 + tid;
            int row = f >> 2;
            int k4 = (f & 3) << 2;
            float4 v = *(const float4*)(Asrc + (long)(m0 + row) * lda + acol + k4);
            Asb[k4 + 0][row] = v.x; Asb[k4 + 1][row] = v.y;
            Asb[k4 + 2][row] = v.z; Asb[k4 + 3][row] = v.w;
        }
        if constexpr (BT) {
#pragma unroll
            for (int i = 0; i < 2; ++i) {
                int f = i * 256 + tid;
                int row = f >> 2;
                int k4 = (f & 3) << 2;
                float4 v = *(const float4*)(Bb + (long)(n0 + row) * ldb + kk + k4);
                Bsb[k4 + 0][row] = v.x; Bsb[k4 + 1][row] = v.y;
                Bsb[k4 + 2][row] = v.z; Bsb[k4 + 3][row] = v.w;
            }
        } else {
#pragma unroll
            for (int i = 0; i < 2; ++i) {
                int f = i * 256 + tid;
                int kr = f >> 5;
                int n4 = (f & 31) << 2;
                float4 v = *(const float4*)(Bb + (long)(kk + kr) * ldb + n0 + n4);
                *(float4*)&Bsb[kr][n4] = v;
            }
        }
        __syncthreads();
#pragma unroll
        for (int k = 0; k < BKT; ++k) {
            float a[8], bv[8];
            *(float4*)&a[0]  = *(const float4*)&Asb[k][ty * 4];
            *(float4*)&a[4]  = *(const float4*)&Asb[k][ty * 4 + 64];
            *(float4*)&bv[0] = *(const float4*)&Bsb[k][tx * 4];
            *(float4*)&bv[4] = *(const float4*)&Bsb[k][tx * 4 + 64];
#pragma unroll
            for (int i = 0; i < 8; ++i)
#pragma unroll
                for (int j = 0; j < 8; ++j)
                    acc[i][j] = fmaf(a[i], bv[j], acc[i][j]);
        }
        __syncthreads();
    }
#pragma unroll
    for (int i = 0; i < 8; ++i) {
        int rrow = m0 + ty * 4 + (i & 3) + ((i >> 2) << 6);
        float* crow = Cb + (long)rrow * ldc;
#pragma unroll
        for (int jj = 0; jj < 2; ++jj) {
            int c0 = n0 + tx * 4 + jj * 64;
            float4 v;
            v.x = acc[i][jj * 4 + 0]; v.y = acc[i][jj * 4 + 1];
            v.z = acc[i][jj * 4 + 2]; v.w = acc[i][jj * 4 + 3];
            if constexpr (DO_TANH) {
                v.x = tanhf(v.x + bias[c0 + 0]); v.y = tanhf(v.y + bias[c0 + 1]);
                v.z = tanhf(v.z + bias[c0 + 2]); v.w = tanhf(v.w + bias[c0 + 3]);
            }
            *(float4*)(crow + c0) = v;
        }
    }
}

__global__ __launch_bounds__(256)
void softmax_rows(float* __restrict__ P)
{
    const int row = blockIdx.x * 4 + (threadIdx.x >> 6);
    const int lane = threadIdx.x & 63;
    float* p = P + (long)row * 1024 + lane * 4;
    float4 v[4];
    float mx = -INFINITY;
#pragma unroll
    for (int i = 0; i < 4; ++i) {
        v[i] = *(const float4*)(p + i * 256);
        v[i].x = (v[i].x == 0.f) ? -INFINITY : v[i].x;
        v[i].y = (v[i].y == 0.f) ? -INFINITY : v[i].y;
        v[i].z = (v[i].z == 0.f) ? -INFINITY : v[i].z;
        v[i].w = (v[i].w == 0.f) ? -INFINITY : v[i].w;
        mx = fmaxf(mx, fmaxf(fmaxf(v[i].x, v[i].y), fmaxf(v[i].z, v[i].w)));
    }
#pragma unroll
    for (int o = 32; o > 0; o >>= 1) mx = fmaxf(mx, __shfl_xor(mx, o, 64));
    float sum = 0.f;
#pragma unroll
    for (int i = 0; i < 4; ++i) {
        v[i].x = __expf(v[i].x - mx); v[i].y = __expf(v[i].y - mx);
        v[i].z = __expf(v[i].z - mx); v[i].w = __expf(v[i].w - mx);
        sum += v[i].x + v[i].y + v[i].z + v[i].w;
    }
#pragma unroll
    for (int o = 32; o > 0; o >>= 1) sum += __shfl_xor(sum, o, 64);
    const float inv = 1.f / sum;
#pragma unroll
    for (int i = 0; i < 4; ++i) {
        v[i].x *= inv; v[i].y *= inv; v[i].z *= inv; v[i].w *= inv;
        *(float4*)(p + i * 256) = v[i];
    }
}

// ================================================================ launch
extern "C" void kernel_launch(void* const* d_in, const int* in_sizes, int n_in,
                              void* d_out, int out_size, void* d_ws, size_t ws_size,
                              hipStream_t stream)
{
    (void)in_sizes; (void)n_in; (void)out_size;
    const int Bv = 32, T = 512, S = 1024, H = 1024;

    const float* q     = (const float*)d_in[0];
    const float* enc   = (const float*)d_in[1];
    const float* W_in  = (const float*)d_in[3];
    const float* W_out = (const float*)d_in[4];
    const float* b_out = (const float*)d_in[5];
    float* out = (float*)d_out;

    const size_t need = 264ull << 20;
    if (ws_size >= need) {
        char* w = (char*)d_ws;
        unsigned short* q_hi  = (unsigned short*)(w);                  // K1
        unsigned short* q_lo  = (unsigned short*)(w + (32ull << 20));  // K1; then Pb fp16
        unsigned short* z_hi  = (unsigned short*)(w + (64ull << 20));  // K1->K2; then C_f16
        unsigned short* z_lo  = (unsigned short*)(w + (96ull << 20));  // K1->K2; then q_f16
        unsigned short* e_hi  = (unsigned short*)(w + (128ull << 20)); // K2
        unsigned short* e_lo  = (unsigned short*)(w + (192ull << 20)); // K2; then eT fp16
        unsigned short* Wi_hi = (unsigned short*)(w + (256ull << 20));
        unsigned short* Wi_lo = (unsigned short*)(w + (258ull << 20));
        unsigned short* Wo16  = (unsigned short*)(w + (260ull << 20));

        unsigned short* Pb    = q_lo;   // fp16, after softmax
        unsigned short* q16   = z_lo;   // fp16, after K2
        unsigned short* eT    = e_lo;   // fp16, after K2
        unsigned short* C16   = z_hi;   // fp16, after K2

        split_f32_bf16<true ><<<16384, 256, 0, stream>>>(q, q_hi, q_lo, 4194304);
        split_f32_bf16<true ><<<1024,  256, 0, stream>>>(W_in, Wi_hi, Wi_lo, 262144);
        conv_f32_f16<<<2048, 256, 0, stream>>>(W_out, Wo16, 524288);
        split_f32_bf16<true ><<<32768, 256, 0, stream>>>(enc, e_hi, e_lo, 8388608);

        // K1: z = q·W_in^T  (chunk-fused bf16x3), out z_hi/z_lo
        gemm_x3<1><<<dim3(8, 128, 1), 256, 0, stream>>>(
            q_hi, q_lo, Wi_hi, Wi_lo,
            nullptr, z_hi, z_lo,
            1024, 1024, 1024, 1024, 0, 0, 0);

        // K2: P_b = z_b·enc_b^T (chunk-fused bf16x3), fp32 -> d_out
        gemm_x3<2><<<dim3(8, 4, 32), 256, 0, stream>>>(
            z_hi, z_lo, e_hi, e_lo,
            (float*)d_out, nullptr, nullptr,
            1024, 1024, (long)Bv * H, 1024,
            (long)T * H, (long)H, (long)T * S);

        // K3: masked softmax, fp32 -> fp16 Pb
        softmax_p_f16<<<(Bv * T) / 4, 256, 0, stream>>>((const float*)d_out, Pb);

        // q fp32 -> fp16 (into z_lo, free after K2)
        conv_f32_f16<<<16384, 256, 0, stream>>>(q, q16, 4194304);

        // enc fp32 [S,B,H] -> eT fp16 [B][H][S] (into e_lo, free after K2)
        transpose_enc_f16<<<dim3(16, 16, 32), 256, 0, stream>>>(enc, eT);

        // K4: C_b = Pb_b · eT_b^T  (fp16), out C_f16
        gemm_f16<1, 0><<<dim3(8, 4, 32), 256, 0, stream>>>(
            Pb, nullptr, eT, nullptr,
            nullptr, C16, nullptr,
            1024, 1024, 1024, 1024,
            (long)T * S, (long)H * S, (long)T * H);

        // K5: out = tanh([C,q]·W_out^T + b)  (fp16, 2 chunks of K=1024)
        gemm_f16<2, 3><<<dim3(8, 128, 1), 256, 0, stream>>>(
            C16, q16, Wo16, Wo16 + 1024,
            (float*)d_out, nullptr, b_out,
            1024, 1024, 2048, 1024, 0, 0, 0);
    } else {
        // -------- fallback: round-1 fp32 path --------
        float* Z = (float*)d_ws;
        float* P = Z + (size_t)Bv * T * H;
        dim3 blk(256);
        sgemm<true, false, false><<<dim3(H / BN, (Bv * T) / BM, 1), blk, 0, stream>>>(
            q, nullptr, W_in, nullptr, Z,
            Bv * T, H, H, 0, H, H, H, 0, 0, 0);
        sgemm<true, false, false><<<dim3(S / BN, T / BM, Bv), blk, 0, stream>>>(
            Z, nullptr, enc, nullptr, P,
            T, S, H, 0, H, Bv * H, S, (long)T * H, H, (long)T * S);
        softmax_rows<<<(Bv * T) / 4, blk, 0, stream>>>(P);
        sgemm<false, false, false><<<dim3(H / BN, T / BM, Bv), blk, 0, stream>>>(
            P, nullptr, enc, nullptr, Z,
            T, H, S, 0, S, Bv * H, H, (long)T * S, H, (long)T * H);
        sgemm<true, true, true><<<dim3(H / BN, (Bv * T) / BM, 1), blk, 0, stream>>>(
            Z, q, W_out, b_out, out,
            Bv * T, H, 2 * H, H, H, 2 * H, H, 0, 0, 0);
    }
}